// Round 21
// baseline (154.860 us; speedup 1.0000x reference)
//
#include <hip/hip_runtime.h>
#include <hip/hip_bf16.h>

typedef __bf16 bf16;
typedef bf16 bf16x8 __attribute__((ext_vector_type(8)));
typedef bf16 bf16x4 __attribute__((ext_vector_type(4)));
typedef float f32x4 __attribute__((ext_vector_type(4)));

#define CB 16
#define CC 256
#define CH 64
#define CW 64
#define CN 4096
#define NHEADS 8
#define NPOINTS 4
#define HDIM 32

#define MFMA16(a, b, c) __builtin_amdgcn_mfma_f32_16x16x32_bf16(a, b, c, 0, 0, 0)

// async global->LDS, 16B per lane; LDS dest = wave-uniform base + lane*16
__device__ __forceinline__ void gload16(const void* g, void* l) {
    __builtin_amdgcn_global_load_lds((const __attribute__((address_space(1))) void*)g,
                                     (__attribute__((address_space(3))) void*)l, 16, 0, 0);
}

// ---------------- PE table + weight packing (merged, one dispatch) ----------------
__global__ __launch_bounds__(256) void pe_pack(float* __restrict__ pe,
                                               const float* __restrict__ Wv,
                                               const float* __restrict__ Woff,
                                               const float* __restrict__ Wattn,
                                               const float* __restrict__ Wout,
                                               bf16* __restrict__ Wv_bf,
                                               bf16* __restrict__ W96_bf,
                                               bf16* __restrict__ Wout_bf) {
    int idx = blockIdx.x * 256 + threadIdx.x;
    if (idx < CC * CN) {
        int c = idx >> 12, n = idx & (CN - 1);
        int r = n >> 6, x = n & 63;
        int i = c >> 2, t = c & 3;
        float div = __expf(-logf(10000.0f) * (float)i / 64.0f);
        float arg = ((t < 2) ? (float)(x + 1) : (float)(r + 1)) * div;
        pe[idx] = (t & 1) ? cosf(arg) : sinf(arg);
    }
    if (idx < CC * CC) {
        Wv_bf[idx] = (bf16)Wv[idx];
        Wout_bf[idx] = (bf16)Wout[idx];
    }
    if (idx < 96 * CC) {
        W96_bf[idx] = (bf16)((idx < 64 * CC) ? Woff[idx] : Wattn[idx - 64 * CC]);
    }
}

// ---------------- co-dispatched: vproj (y<2) + oa-GEMM/softmax/table (y==2) -----------------
// Independent work flavors in ONE dispatch so latency bubbles of one fill with the other.
__global__ __launch_bounds__(256) void vproj_oa(const float* __restrict__ value,
                                                const bf16* __restrict__ Wv,
                                                const float* __restrict__ bv,
                                                bf16* __restrict__ v_s,
                                                const float* __restrict__ query,
                                                const float* __restrict__ pe,
                                                const bf16* __restrict__ W96,
                                                const float* __restrict__ boff,
                                                const float* __restrict__ battn,
                                                unsigned* __restrict__ tbl_g) {
    __shared__ __align__(16) char smem[33792];
    int tid = threadIdx.x, lane = tid & 63, wave = tid >> 6;
    int wm = wave >> 1, wn = wave & 1, g = lane >> 4, lr = lane & 15;
    int b = blockIdx.z;

    if (blockIdx.y < 2) {
        // ================= vproj branch (r19 vproj_g, byte-identical logic) =================
        float* T = (float*)smem;
        const int TP = 66;
        int n0 = blockIdx.x * 64, m0 = blockIdx.y * 128;
        int nl = tid & 63, kg = tid >> 6;
        const float* src = value + (size_t)b * CC * CN + n0 + nl;

        float v[16];
#pragma unroll
        for (int p = 0; p < 16; ++p) v[p] = src[(size_t)(kg * 16 + p) * CN];

        f32x4 acc[4][2] = {};
        for (int t = 0; t < 4; ++t) {
#pragma unroll
            for (int half = 0; half < 2; ++half) {
                bf16x8 o;
#pragma unroll
                for (int p = 0; p < 8; ++p) o[p] = (bf16)v[half * 8 + p];
                int slot = (kg * 2 + half) ^ (nl & 7);
                *(bf16x8*)(smem + (t & 1) * 8192 + nl * 128 + slot * 16) = o;
            }
            __syncthreads();
            if (t < 3) {
#pragma unroll
                for (int p = 0; p < 16; ++p)
                    v[p] = src[(size_t)((t + 1) * 64 + kg * 16 + p) * CN];
            }
#pragma unroll
            for (int ks = 0; ks < 2; ++ks) {
                bf16x8 af[4], bfr[2];
#pragma unroll
                for (int mf = 0; mf < 4; ++mf)
                    af[mf] = *(const bf16x8*)&Wv[(size_t)(m0 + wm * 64 + mf * 16 + lr) * CC + t * 64 + ks * 32 + g * 8];
#pragma unroll
                for (int nf = 0; nf < 2; ++nf) {
                    int row = wn * 32 + nf * 16 + lr;
                    bfr[nf] = *(const bf16x8*)(smem + (t & 1) * 8192 + row * 128 + (((ks * 4 + g) ^ (row & 7)) * 16));
                }
#pragma unroll
                for (int mf = 0; mf < 4; ++mf)
#pragma unroll
                    for (int nf = 0; nf < 2; ++nf)
                        acc[mf][nf] = MFMA16(af[mf], bfr[nf], acc[mf][nf]);
            }
        }

#pragma unroll
        for (int pass = 0; pass < 2; ++pass) {
            __syncthreads();
            if (wm == pass) {
#pragma unroll
                for (int mf = 0; mf < 4; ++mf)
#pragma unroll
                    for (int nf = 0; nf < 2; ++nf)
#pragma unroll
                        for (int i = 0; i < 4; ++i)
                            T[(mf * 16 + g * 4 + i) * TP + wn * 32 + nf * 16 + lr] = acc[mf][nf][i];
            }
            __syncthreads();
#pragma unroll
            for (int it = 0; it < 2; ++it) {
                int item = it * 256 + tid;
                int qg = item & 7, n_l = item >> 3;
                int cg = m0 + pass * 64 + qg * 8;
                int head = cg >> 5, dd0 = cg & 31;
                bf16x8 o;
#pragma unroll
                for (int u = 0; u < 8; ++u)
                    o[u] = (bf16)(T[(qg * 8 + u) * TP + n_l] + bv[cg + u]);
                *(bf16x8*)&v_s[(((size_t)b * NHEADS + head) * CN + n0 + n_l) * HDIM + dd0] = o;
            }
        }
        return;
    }

    // ================= oa branch: GEMM1 + softmax/bilinear -> packed table =================
    float* ot = (float*)smem;                    // [96][65], overlays staging after GEMM
    int nt = blockIdx.x;
    int n0 = nt * 64;
    int nl = tid & 63, kg = tid >> 6;
    const float* qs = query + (size_t)b * CC * CN + n0 + nl;
    const float* ps = pe + n0 + nl;

    float v[16];
#pragma unroll
    for (int p = 0; p < 16; ++p) {
        size_t off = (size_t)(kg * 16 + p) * CN;
        v[p] = __builtin_nontemporal_load(&qs[off]) + ps[off];
    }
    asm volatile("" ::: "memory");

    f32x4 acc[3][2] = {};
    for (int t = 0; t < 4; ++t) {
#pragma unroll
        for (int half = 0; half < 2; ++half) {
            bf16x8 o;
#pragma unroll
            for (int p = 0; p < 8; ++p) o[p] = (bf16)v[half * 8 + p];
            int slot = (kg * 2 + half) ^ (nl & 7);
            *(bf16x8*)(smem + (t & 1) * 8192 + nl * 128 + slot * 16) = o;
        }
        __syncthreads();
        if (t < 3) {
#pragma unroll
            for (int p = 0; p < 16; ++p) {
                size_t off = (size_t)((t + 1) * 64 + kg * 16 + p) * CN;
                v[p] = __builtin_nontemporal_load(&qs[off]) + ps[off];
            }
            asm volatile("" ::: "memory");
        }
#pragma unroll
        for (int ks = 0; ks < 2; ++ks) {
            bf16x8 af[3], bfr[2];
#pragma unroll
            for (int mf = 0; mf < 3; ++mf)
                af[mf] = *(const bf16x8*)&W96[(size_t)(wm * 48 + mf * 16 + lr) * CC + t * 64 + ks * 32 + g * 8];
#pragma unroll
            for (int nf = 0; nf < 2; ++nf) {
                int row = wn * 32 + nf * 16 + lr;
                bfr[nf] = *(const bf16x8*)(smem + (t & 1) * 8192 + row * 128 + (((ks * 4 + g) ^ (row & 7)) * 16));
            }
#pragma unroll
            for (int mf = 0; mf < 3; ++mf)
#pragma unroll
                for (int nf = 0; nf < 2; ++nf)
                    acc[mf][nf] = MFMA16(af[mf], bfr[nf], acc[mf][nf]);
        }
    }
    __syncthreads();

#pragma unroll
    for (int mf = 0; mf < 3; ++mf) {
#pragma unroll
        for (int i = 0; i < 4; ++i) {
            int j = wm * 48 + mf * 16 + g * 4 + i;
            float bias = (j < 64) ? boff[j] : battn[j - 64];
#pragma unroll
            for (int nf = 0; nf < 2; ++nf) {
                int col = wn * 32 + nf * 16 + lr;
                ot[j * 65 + col] = acc[mf][nf][i] + bias;
            }
        }
    }
    __syncthreads();

    // softmax + bilinear -> packed table (h-major mapping for coalesced global writes)
#pragma unroll
    for (int it = 0; it < 2; ++it) {
        int item = it * 256 + tid;
        int h = item & 7, inl = item >> 3;
        float lg0 = ot[(64 + h * 4 + 0) * 65 + inl];
        float lg1 = ot[(64 + h * 4 + 1) * 65 + inl];
        float lg2 = ot[(64 + h * 4 + 2) * 65 + inl];
        float lg3 = ot[(64 + h * 4 + 3) * 65 + inl];
        float m = fmaxf(fmaxf(lg0, lg1), fmaxf(lg2, lg3));
        float e0 = __expf(lg0 - m), e1 = __expf(lg1 - m);
        float e2 = __expf(lg2 - m), e3 = __expf(lg3 - m);
        float inv = 1.0f / (e0 + e1 + e2 + e3);
        float ep[4] = {e0, e1, e2, e3};
        uint4* dst = (uint4*)(tbl_g + ((size_t)b * CN + n0 + inl) * 128 + h * 16);
#pragma unroll
        for (int p = 0; p < NPOINTS; ++p) {
            float off0 = ot[(h * 8 + p * 2 + 0) * 65 + inl];
            float off1 = ot[(h * 8 + p * 2 + 1) * 65 + inl];
            float ix = (float)inl * (64.0f / 63.0f) + off0 - 0.5f;
            float iy = (float)nt * (64.0f / 63.0f) + off1 - 0.5f;
            float x0f = floorf(ix), y0f = floorf(iy);
            float wx = ix - x0f, wy = iy - y0f;
            int x0 = (int)x0f, y0 = (int)y0f;
            int x1 = x0 + 1, y1 = y0 + 1;
            float vx0 = (x0 >= 0 && x0 < CW) ? 1.f : 0.f;
            float vx1 = (x1 >= 0 && x1 < CW) ? 1.f : 0.f;
            float vy0 = (y0 >= 0 && y0 < CH) ? 1.f : 0.f;
            float vy1 = (y1 >= 0 && y1 < CH) ? 1.f : 0.f;
            int x0c = min(max(x0, 0), CW - 1), x1c = min(max(x1, 0), CW - 1);
            int y0c = min(max(y0, 0), CH - 1), y1c = min(max(y1, 0), CH - 1);
            float a = ep[p] * inv;
            float w00 = a * (1.f - wx) * (1.f - wy) * vx0 * vy0;
            float w01 = a * wx * (1.f - wy) * vx1 * vy0;
            float w10 = a * (1.f - wx) * wy * vx0 * vy1;
            float w11 = a * wx * wy * vx1 * vy1;
            uint4 w4;
            w4.x = ((unsigned)__builtin_bit_cast(unsigned short, (_Float16)w00) << 16) | (unsigned)(y0c * CW + x0c);
            w4.y = ((unsigned)__builtin_bit_cast(unsigned short, (_Float16)w01) << 16) | (unsigned)(y0c * CW + x1c);
            w4.z = ((unsigned)__builtin_bit_cast(unsigned short, (_Float16)w10) << 16) | (unsigned)(y1c * CW + x0c);
            w4.w = ((unsigned)__builtin_bit_cast(unsigned short, (_Float16)w11) << 16) | (unsigned)(y1c * CW + x1c);
            dst[p] = w4;
        }
    }
}

// ---------------- sampling: pure gather kernel (no LDS), XCD-chunked ----------------
__global__ __launch_bounds__(256, 4) void sample_k(const unsigned* __restrict__ tbl_g,
                                                   const bf16* __restrict__ v_s,
                                                   bf16* __restrict__ s) {
    int tid = threadIdx.x;
    int id = blockIdx.x;
    int xcd = id & 7, local = id >> 3;           // XCD j owns batches {2j, 2j+1}
    int b = xcd * 2 + (local >> 6);
    int nt = local & 63;
    int n0 = nt * 64;
    int q = tid & 3, h2 = (tid >> 2) & 7, ng = tid >> 5;
    const bf16* vb = v_s + (((size_t)b * NHEADS + h2) * CN) * HDIM + q * 8;
#pragma unroll
    for (int iter = 0; iter < 8; ++iter) {
        int snl = iter * 8 + ng;
        const uint4* tb4 = (const uint4*)(tbl_g + ((size_t)b * CN + n0 + snl) * 128 + h2 * 16);
        unsigned ue[16];
#pragma unroll
        for (int j = 0; j < 4; ++j) {
            uint4 t4 = tb4[j];
            ue[j * 4 + 0] = t4.x; ue[j * 4 + 1] = t4.y;
            ue[j * 4 + 2] = t4.z; ue[j * 4 + 3] = t4.w;
        }
        asm volatile("" ::: "memory");
        bf16x8 gr[16];
#pragma unroll
        for (int e = 0; e < 16; ++e)
            gr[e] = *(const bf16x8*)&vb[(int)(ue[e] & 0xFFFu) * HDIM];
        asm volatile("" ::: "memory");
        float a0 = 0.f, a1 = 0.f, a2 = 0.f, a3 = 0.f;
        float a4 = 0.f, a5 = 0.f, a6 = 0.f, a7 = 0.f;
#pragma unroll
        for (int e = 0; e < 16; ++e) {
            float w = (float)__builtin_bit_cast(_Float16, (unsigned short)(ue[e] >> 16));
            a0 += w * (float)gr[e][0]; a1 += w * (float)gr[e][1];
            a2 += w * (float)gr[e][2]; a3 += w * (float)gr[e][3];
            a4 += w * (float)gr[e][4]; a5 += w * (float)gr[e][5];
            a6 += w * (float)gr[e][6]; a7 += w * (float)gr[e][7];
        }
        bf16x8 o;
        o[0] = (bf16)a0; o[1] = (bf16)a1; o[2] = (bf16)a2; o[3] = (bf16)a3;
        o[4] = (bf16)a4; o[5] = (bf16)a5; o[6] = (bf16)a6; o[7] = (bf16)a7;
        *(bf16x8*)&s[((size_t)b * CN + n0 + snl) * CC + h2 * 32 + q * 8] = o;
    }
}

// ---------------- output proj v8: BK=32 double-buffered gload_lds pipeline ------------------
__global__ __launch_bounds__(256) void outproj_v8(const bf16* __restrict__ s_t,
                                                  const bf16* __restrict__ Wout,
                                                  const float* __restrict__ bout,
                                                  const float* __restrict__ query,
                                                  const float* __restrict__ pe,
                                                  float* __restrict__ out) {
    __shared__ __align__(16) char smem[33792];
    float* T = (float*)smem;
    const int TP = 132;

    int tid = threadIdx.x, lane = tid & 63, wave = tid >> 6;
    int wm = wave >> 1, wn = wave & 1, g = lane >> 4, lr = lane & 15;
    int id = blockIdx.x;
    int swz = (id & 7) * 128 + (id >> 3);
    int n0 = (swz & 31) * 128, c0 = ((swz >> 5) & 1) * 128, b = swz >> 6;
    const bf16* sb = s_t + ((size_t)b * CN + n0) * CC;

    int rloc = lane >> 2, sl = lane & 3;

    auto stage = [&](int t, int bsel) {
#pragma unroll
        for (int j = 0; j < 2; ++j) {
            int cidx = wave * 2 + j;
            int row = cidx * 16 + rloc;
            int chunk = sl ^ (row & 3);
            const bf16* gA = sb + (size_t)row * CC + t * 32 + chunk * 8;
            const bf16* gB = Wout + (size_t)(c0 + row) * CC + t * 32 + chunk * 8;
            gload16(gA, smem + bsel * 16384 + cidx * 1024);
            gload16(gB, smem + bsel * 16384 + 8192 + cidx * 1024);
        }
    };

    stage(0, 0);

    f32x4 acc[4][4] = {};
    for (int t = 0; t < 8; ++t) {
        __syncthreads();
        if (t < 7) stage(t + 1, (t + 1) & 1);
        bf16x8 af[4], bfr[4];
#pragma unroll
        for (int mf = 0; mf < 4; ++mf) {
            int row = wm * 64 + mf * 16 + lr;
            af[mf] = *(const bf16x8*)(smem + (t & 1) * 16384 + row * 64 + ((g ^ (row & 3)) * 16));
        }
#pragma unroll
        for (int nf = 0; nf < 4; ++nf) {
            int row = wn * 64 + nf * 16 + lr;
            bfr[nf] = *(const bf16x8*)(smem + (t & 1) * 16384 + 8192 + row * 64 + ((g ^ (row & 3)) * 16));
        }
#pragma unroll
        for (int mf = 0; mf < 4; ++mf)
#pragma unroll
            for (int nf = 0; nf < 4; ++nf)
                acc[mf][nf] = MFMA16(af[mf], bfr[nf], acc[mf][nf]);
    }
    __syncthreads();

    int lr5 = tid & 31, rq = tid >> 5;
#pragma unroll
    for (int ch = 0; ch < 2; ++ch) {
        if (wn == ch) {
#pragma unroll
            for (int mf = 0; mf < 4; ++mf)
#pragma unroll
                for (int nf = 0; nf < 4; ++nf) {
                    int cl = nf * 16 + lr;
                    int nl = wm * 64 + mf * 16 + g * 4;
                    *(f32x4*)&T[cl * TP + nl] = acc[mf][nf];
                }
        }
        __syncthreads();
#pragma unroll
        for (int pass = 0; pass < 8; ++pass) {
            int cl = pass * 8 + rq;
            int c = c0 + ch * 64 + cl;
            int n = n0 + lr5 * 4;
            f32x4 v = *(const f32x4*)&T[cl * TP + lr5 * 4];
            size_t base = ((size_t)b * CC + c) * CN + n;
            f32x4 q4 = *(const f32x4*)&query[base];
            f32x4 p4 = *(const f32x4*)&pe[(size_t)c * CN + n];
            float bias = bout[c];
#pragma unroll
            for (int j = 0; j < 4; ++j) v[j] = v[j] + bias + 2.0f * (q4[j] + p4[j]);
            *(f32x4*)&out[base] = v;
        }
        __syncthreads();
    }
}

extern "C" void kernel_launch(void* const* d_in, const int* in_sizes, int n_in,
                              void* d_out, int out_size, void* d_ws, size_t ws_size,
                              hipStream_t stream) {
    const float* query = (const float*)d_in[0];
    const float* value = (const float*)d_in[1];
    const float* W_off = (const float*)d_in[2];
    const float* b_off = (const float*)d_in[3];
    const float* W_attn = (const float*)d_in[4];
    const float* b_attn = (const float*)d_in[5];
    const float* W_val = (const float*)d_in[6];
    const float* b_val = (const float*)d_in[7];
    const float* W_out = (const float*)d_in[8];
    const float* b_out = (const float*)d_in[9];
    float* out = (float*)d_out;

    char* p = (char*)d_ws;
    float* pe = (float*)p;            p += (size_t)CC * CN * 4;
    bf16* Wv_bf = (bf16*)p;           p += (size_t)CC * CC * 2;
    bf16* Wout_bf = (bf16*)p;         p += (size_t)CC * CC * 2;
    bf16* W96_bf = (bf16*)p;          p += (size_t)96 * CC * 2 + 256;
    bf16* v_s = (bf16*)p;             p += (size_t)CB * NHEADS * CN * HDIM * 2;
    bf16* s_t = (bf16*)p;             p += (size_t)CB * CN * CC * 2;
    unsigned* tbl_g = (unsigned*)p;   p += (size_t)CB * CN * 128 * 4;

    pe_pack<<<dim3((CC * CN + 255) / 256), dim3(256), 0, stream>>>(pe, W_val, W_off, W_attn,
                                                                   W_out, Wv_bf, W96_bf, Wout_bf);
    vproj_oa<<<dim3(CN / 64, 3, CB), dim3(256), 0, stream>>>(value, Wv_bf, b_val, v_s,
                                                             query, pe, W96_bf, b_off, b_attn,
                                                             tbl_g);
    sample_k<<<dim3(1024), dim3(256), 0, stream>>>(tbl_g, v_s, s_t);
    outproj_v8<<<dim3(1024), dim3(256), 0, stream>>>(s_t, Wout_bf, b_out, query, pe, out);
}

// Round 22
// 134.608 us; speedup vs baseline: 1.1505x; 1.1505x over previous
//
#include <hip/hip_runtime.h>
#include <hip/hip_bf16.h>

typedef __bf16 bf16;
typedef bf16 bf16x8 __attribute__((ext_vector_type(8)));
typedef bf16 bf16x4 __attribute__((ext_vector_type(4)));
typedef float f32x4 __attribute__((ext_vector_type(4)));

#define CB 16
#define CC 256
#define CH 64
#define CW 64
#define CN 4096
#define NHEADS 8
#define NPOINTS 4
#define HDIM 32
#define TBP 132   // table pitch (u32), 16B-aligned rows for uint4 access

#define MFMA16(a, b, c) __builtin_amdgcn_mfma_f32_16x16x32_bf16(a, b, c, 0, 0, 0)

// async global->LDS, 16B per lane; LDS dest = wave-uniform base + lane*16
__device__ __forceinline__ void gload16(const void* g, void* l) {
    __builtin_amdgcn_global_load_lds((const __attribute__((address_space(1))) void*)g,
                                     (__attribute__((address_space(3))) void*)l, 16, 0, 0);
}

// ---------------- PE table + weight packing (merged, one dispatch) ----------------
__global__ __launch_bounds__(256) void pe_pack(float* __restrict__ pe,
                                               const float* __restrict__ Wv,
                                               const float* __restrict__ Woff,
                                               const float* __restrict__ Wattn,
                                               const float* __restrict__ Wout,
                                               bf16* __restrict__ Wv_bf,
                                               bf16* __restrict__ W96_bf,
                                               bf16* __restrict__ Wout_bf) {
    int idx = blockIdx.x * 256 + threadIdx.x;
    if (idx < CC * CN) {
        int c = idx >> 12, n = idx & (CN - 1);
        int r = n >> 6, x = n & 63;
        int i = c >> 2, t = c & 3;
        float div = __expf(-logf(10000.0f) * (float)i / 64.0f);
        float arg = ((t < 2) ? (float)(x + 1) : (float)(r + 1)) * div;
        pe[idx] = (t & 1) ? cosf(arg) : sinf(arg);
    }
    if (idx < CC * CC) {
        Wv_bf[idx] = (bf16)Wv[idx];
        Wout_bf[idx] = (bf16)Wout[idx];
    }
    if (idx < 96 * CC) {
        W96_bf[idx] = (bf16)((idx < 64 * CC) ? Woff[idx] : Wattn[idx - 64 * CC]);
    }
}

// ---------------- value projection: 256-thread blocks, BM=128 ----------------
__global__ __launch_bounds__(256) void vproj_g(const float* __restrict__ value,
                                               const bf16* __restrict__ Wv,
                                               const float* __restrict__ bv,
                                               bf16* __restrict__ v_s) {
    __shared__ __align__(16) char smem[17408];
    float* T = (float*)smem;
    const int TP = 66;

    int tid = threadIdx.x, lane = tid & 63, wave = tid >> 6;
    int wm = wave >> 1, wn = wave & 1, g = lane >> 4, lr = lane & 15;
    int n0 = blockIdx.x * 64, m0 = blockIdx.y * 128, b = blockIdx.z;
    int nl = tid & 63, kg = tid >> 6;
    const float* src = value + (size_t)b * CC * CN + n0 + nl;

    float v[16];
#pragma unroll
    for (int p = 0; p < 16; ++p) v[p] = src[(size_t)(kg * 16 + p) * CN];

    f32x4 acc[4][2] = {};
    for (int t = 0; t < 4; ++t) {
#pragma unroll
        for (int half = 0; half < 2; ++half) {
            bf16x8 o;
#pragma unroll
            for (int p = 0; p < 8; ++p) o[p] = (bf16)v[half * 8 + p];
            int slot = (kg * 2 + half) ^ (nl & 7);
            *(bf16x8*)(smem + (t & 1) * 8192 + nl * 128 + slot * 16) = o;
        }
        __syncthreads();
        if (t < 3) {
#pragma unroll
            for (int p = 0; p < 16; ++p)
                v[p] = src[(size_t)((t + 1) * 64 + kg * 16 + p) * CN];
        }
#pragma unroll
        for (int ks = 0; ks < 2; ++ks) {
            bf16x8 af[4], bfr[2];
#pragma unroll
            for (int mf = 0; mf < 4; ++mf)
                af[mf] = *(const bf16x8*)&Wv[(size_t)(m0 + wm * 64 + mf * 16 + lr) * CC + t * 64 + ks * 32 + g * 8];
#pragma unroll
            for (int nf = 0; nf < 2; ++nf) {
                int row = wn * 32 + nf * 16 + lr;
                bfr[nf] = *(const bf16x8*)(smem + (t & 1) * 8192 + row * 128 + (((ks * 4 + g) ^ (row & 7)) * 16));
            }
#pragma unroll
            for (int mf = 0; mf < 4; ++mf)
#pragma unroll
                for (int nf = 0; nf < 2; ++nf)
                    acc[mf][nf] = MFMA16(af[mf], bfr[nf], acc[mf][nf]);
        }
    }

#pragma unroll
    for (int pass = 0; pass < 2; ++pass) {
        __syncthreads();
        if (wm == pass) {
#pragma unroll
            for (int mf = 0; mf < 4; ++mf)
#pragma unroll
                for (int nf = 0; nf < 2; ++nf)
#pragma unroll
                    for (int i = 0; i < 4; ++i)
                        T[(mf * 16 + g * 4 + i) * TP + wn * 32 + nf * 16 + lr] = acc[mf][nf][i];
        }
        __syncthreads();
#pragma unroll
        for (int it = 0; it < 2; ++it) {
            int item = it * 256 + tid;
            int qg = item & 7, n_l = item >> 3;
            int cg = m0 + pass * 64 + qg * 8;
            int head = cg >> 5, dd0 = cg & 31;
            bf16x8 o;
#pragma unroll
            for (int u = 0; u < 8; ++u)
                o[u] = (bf16)(T[(qg * 8 + u) * TP + n_l] + bv[cg + u]);
            *(bf16x8*)&v_s[(((size_t)b * NHEADS + head) * CN + n0 + n_l) * HDIM + dd0] = o;
        }
    }
}

// ---------------- fused off+attn+sampling: batched gathers + XCD grid + NT query ------------
__global__ __launch_bounds__(256, 4) void offattn_sample(const float* __restrict__ query,
                                                         const float* __restrict__ pe,
                                                         const bf16* __restrict__ W96,
                                                         const float* __restrict__ boff,
                                                         const float* __restrict__ battn,
                                                         const bf16* __restrict__ v_s,
                                                         bf16* __restrict__ s) {
    __shared__ __align__(16) char smem[33792];
    float* ot = (float*)smem;
    unsigned* tbl = (unsigned*)smem;

    int tid = threadIdx.x, lane = tid & 63, wave = tid >> 6;
    int wm = wave >> 1, wn = wave & 1, g = lane >> 4, lr = lane & 15;
    int id = blockIdx.x;
    int xcd = id & 7, local = id >> 3;
    int b = xcd * 2 + (local >> 6);
    int nt = local & 63;
    int n0 = nt * 64;
    int nl = tid & 63, kg = tid >> 6;
    const float* qs = query + (size_t)b * CC * CN + n0 + nl;
    const float* ps = pe + n0 + nl;

    float v[16];
#pragma unroll
    for (int p = 0; p < 16; ++p) {
        size_t off = (size_t)(kg * 16 + p) * CN;
        v[p] = __builtin_nontemporal_load(&qs[off]) + ps[off];
    }
    asm volatile("" ::: "memory");

    f32x4 acc[3][2] = {};
    for (int t = 0; t < 4; ++t) {
#pragma unroll
        for (int half = 0; half < 2; ++half) {
            bf16x8 o;
#pragma unroll
            for (int p = 0; p < 8; ++p) o[p] = (bf16)v[half * 8 + p];
            int slot = (kg * 2 + half) ^ (nl & 7);
            *(bf16x8*)(smem + (t & 1) * 8192 + nl * 128 + slot * 16) = o;
        }
        __syncthreads();
        if (t < 3) {
#pragma unroll
            for (int p = 0; p < 16; ++p) {
                size_t off = (size_t)((t + 1) * 64 + kg * 16 + p) * CN;
                v[p] = __builtin_nontemporal_load(&qs[off]) + ps[off];
            }
            asm volatile("" ::: "memory");
        }
#pragma unroll
        for (int ks = 0; ks < 2; ++ks) {
            bf16x8 af[3], bfr[2];
#pragma unroll
            for (int mf = 0; mf < 3; ++mf)
                af[mf] = *(const bf16x8*)&W96[(size_t)(wm * 48 + mf * 16 + lr) * CC + t * 64 + ks * 32 + g * 8];
#pragma unroll
            for (int nf = 0; nf < 2; ++nf) {
                int row = wn * 32 + nf * 16 + lr;
                bfr[nf] = *(const bf16x8*)(smem + (t & 1) * 8192 + row * 128 + (((ks * 4 + g) ^ (row & 7)) * 16));
            }
#pragma unroll
            for (int mf = 0; mf < 3; ++mf)
#pragma unroll
                for (int nf = 0; nf < 2; ++nf)
                    acc[mf][nf] = MFMA16(af[mf], bfr[nf], acc[mf][nf]);
        }
    }
    __syncthreads();

#pragma unroll
    for (int mf = 0; mf < 3; ++mf) {
#pragma unroll
        for (int i = 0; i < 4; ++i) {
            int j = wm * 48 + mf * 16 + g * 4 + i;
            float bias = (j < 64) ? boff[j] : battn[j - 64];
#pragma unroll
            for (int nf = 0; nf < 2; ++nf) {
                int col = wn * 32 + nf * 16 + lr;
                ot[j * 65 + col] = acc[mf][nf][i] + bias;
            }
        }
    }
    __syncthreads();

    unsigned pk[2][16];
#pragma unroll
    for (int it = 0; it < 2; ++it) {
        int item = it * 256 + tid;
        int inl = item & 63, h = item >> 6;
        float lg0 = ot[(64 + h * 4 + 0) * 65 + inl];
        float lg1 = ot[(64 + h * 4 + 1) * 65 + inl];
        float lg2 = ot[(64 + h * 4 + 2) * 65 + inl];
        float lg3 = ot[(64 + h * 4 + 3) * 65 + inl];
        float m = fmaxf(fmaxf(lg0, lg1), fmaxf(lg2, lg3));
        float e0 = __expf(lg0 - m), e1 = __expf(lg1 - m);
        float e2 = __expf(lg2 - m), e3 = __expf(lg3 - m);
        float inv = 1.0f / (e0 + e1 + e2 + e3);
        float ep[4] = {e0, e1, e2, e3};
#pragma unroll
        for (int p = 0; p < NPOINTS; ++p) {
            float off0 = ot[(h * 8 + p * 2 + 0) * 65 + inl];
            float off1 = ot[(h * 8 + p * 2 + 1) * 65 + inl];
            float ix = (float)inl * (64.0f / 63.0f) + off0 - 0.5f;
            float iy = (float)nt * (64.0f / 63.0f) + off1 - 0.5f;
            float x0f = floorf(ix), y0f = floorf(iy);
            float wx = ix - x0f, wy = iy - y0f;
            int x0 = (int)x0f, y0 = (int)y0f;
            int x1 = x0 + 1, y1 = y0 + 1;
            float vx0 = (x0 >= 0 && x0 < CW) ? 1.f : 0.f;
            float vx1 = (x1 >= 0 && x1 < CW) ? 1.f : 0.f;
            float vy0 = (y0 >= 0 && y0 < CH) ? 1.f : 0.f;
            float vy1 = (y1 >= 0 && y1 < CH) ? 1.f : 0.f;
            int x0c = min(max(x0, 0), CW - 1), x1c = min(max(x1, 0), CW - 1);
            int y0c = min(max(y0, 0), CH - 1), y1c = min(max(y1, 0), CH - 1);
            float a = ep[p] * inv;
            float w00 = a * (1.f - wx) * (1.f - wy) * vx0 * vy0;
            float w01 = a * wx * (1.f - wy) * vx1 * vy0;
            float w10 = a * (1.f - wx) * wy * vx0 * vy1;
            float w11 = a * wx * wy * vx1 * vy1;
            unsigned c00 = (unsigned)(y0c * CW + x0c), c01 = (unsigned)(y0c * CW + x1c);
            unsigned c10 = (unsigned)(y1c * CW + x0c), c11 = (unsigned)(y1c * CW + x1c);
            pk[it][p * 4 + 0] = ((unsigned)__builtin_bit_cast(unsigned short, (_Float16)w00) << 16) | c00;
            pk[it][p * 4 + 1] = ((unsigned)__builtin_bit_cast(unsigned short, (_Float16)w01) << 16) | c01;
            pk[it][p * 4 + 2] = ((unsigned)__builtin_bit_cast(unsigned short, (_Float16)w10) << 16) | c10;
            pk[it][p * 4 + 3] = ((unsigned)__builtin_bit_cast(unsigned short, (_Float16)w11) << 16) | c11;
        }
    }
    __syncthreads();
#pragma unroll
    for (int it = 0; it < 2; ++it) {
        int item = it * 256 + tid;
        int inl = item & 63, h = item >> 6;
        uint4* dst = (uint4*)(tbl + inl * TBP + h * 16);
#pragma unroll
        for (int j = 0; j < 4; ++j) {
            uint4 w4;
            w4.x = pk[it][j * 4 + 0]; w4.y = pk[it][j * 4 + 1];
            w4.z = pk[it][j * 4 + 2]; w4.w = pk[it][j * 4 + 3];
            dst[j] = w4;
        }
    }
    __syncthreads();

    int q = tid & 3, h2 = (tid >> 2) & 7, ng = tid >> 5;
    const bf16* vb = v_s + (((size_t)b * NHEADS + h2) * CN) * HDIM + q * 8;
#pragma unroll
    for (int iter = 0; iter < 8; ++iter) {
        int snl = iter * 8 + ng;
        const uint4* tb4 = (const uint4*)(tbl + snl * TBP + h2 * 16);
        unsigned ue[16];
#pragma unroll
        for (int j = 0; j < 4; ++j) {
            uint4 t4 = tb4[j];
            ue[j * 4 + 0] = t4.x; ue[j * 4 + 1] = t4.y;
            ue[j * 4 + 2] = t4.z; ue[j * 4 + 3] = t4.w;
        }
        asm volatile("" ::: "memory");
        bf16x8 gr[16];
#pragma unroll
        for (int e = 0; e < 16; ++e)
            gr[e] = *(const bf16x8*)&vb[(int)(ue[e] & 0xFFFu) * HDIM];
        asm volatile("" ::: "memory");
        float a0 = 0.f, a1 = 0.f, a2 = 0.f, a3 = 0.f;
        float a4 = 0.f, a5 = 0.f, a6 = 0.f, a7 = 0.f;
#pragma unroll
        for (int e = 0; e < 16; ++e) {
            float w = (float)__builtin_bit_cast(_Float16, (unsigned short)(ue[e] >> 16));
            a0 += w * (float)gr[e][0]; a1 += w * (float)gr[e][1];
            a2 += w * (float)gr[e][2]; a3 += w * (float)gr[e][3];
            a4 += w * (float)gr[e][4]; a5 += w * (float)gr[e][5];
            a6 += w * (float)gr[e][6]; a7 += w * (float)gr[e][7];
        }
        bf16x8 o;
        o[0] = (bf16)a0; o[1] = (bf16)a1; o[2] = (bf16)a2; o[3] = (bf16)a3;
        o[4] = (bf16)a4; o[5] = (bf16)a5; o[6] = (bf16)a6; o[7] = (bf16)a7;
        *(bf16x8*)&s[((size_t)b * CN + n0 + snl) * CC + h2 * 32 + q * 8] = o;
    }
}

// ---------------- output proj v7: global_load_lds staging (pre-swizzled source) -------------
__global__ __launch_bounds__(256) void outproj_v7(const bf16* __restrict__ s_t,
                                                  const bf16* __restrict__ Wout,
                                                  const float* __restrict__ bout,
                                                  const float* __restrict__ query,
                                                  const float* __restrict__ pe,
                                                  float* __restrict__ out) {
    __shared__ __align__(16) char smem[33792];
    float* T = (float*)smem;
    const int TP = 132;

    int tid = threadIdx.x, lane = tid & 63, wave = tid >> 6;
    int wm = wave >> 1, wn = wave & 1, g = lane >> 4, lr = lane & 15;
    int id = blockIdx.x;
    int swz = (id & 7) * 128 + (id >> 3);
    int n0 = (swz & 31) * 128, c0 = ((swz >> 5) & 1) * 128, b = swz >> 6;
    const bf16* sb = s_t + ((size_t)b * CN + n0) * CC;

    f32x4 acc[4][4] = {};
    for (int t = 0; t < 4; ++t) {
        if (t) __syncthreads();
#pragma unroll
        for (int j = 0; j < 4; ++j) {
            int blkrow = (wave * 4 + j) * 8;
            int row = blkrow + (lane >> 3);
            int chunk = (lane & 7) ^ (row & 7);
            const bf16* gA = sb + (size_t)row * CC + t * 64 + chunk * 8;
            const bf16* gB = Wout + (size_t)(c0 + row) * CC + t * 64 + chunk * 8;
            gload16(gA, smem + (wave * 4 + j) * 1024);
            gload16(gB, smem + 16384 + (wave * 4 + j) * 1024);
        }
        __syncthreads();
#pragma unroll
        for (int ks = 0; ks < 2; ++ks) {
            bf16x8 af[4], bfr[4];
#pragma unroll
            for (int mf = 0; mf < 4; ++mf) {
                int row = wm * 64 + mf * 16 + lr;
                af[mf] = *(const bf16x8*)(smem + row * 128 + (((ks * 4 + g) ^ (row & 7)) * 16));
            }
#pragma unroll
            for (int nf = 0; nf < 4; ++nf) {
                int row = wn * 64 + nf * 16 + lr;
                bfr[nf] = *(const bf16x8*)(smem + 16384 + row * 128 + (((ks * 4 + g) ^ (row & 7)) * 16));
            }
#pragma unroll
            for (int mf = 0; mf < 4; ++mf)
#pragma unroll
                for (int nf = 0; nf < 4; ++nf)
                    acc[mf][nf] = MFMA16(af[mf], bfr[nf], acc[mf][nf]);
        }
    }
    __syncthreads();

    int lr5 = tid & 31, rq = tid >> 5;
#pragma unroll
    for (int ch = 0; ch < 2; ++ch) {
        if (wn == ch) {
#pragma unroll
            for (int mf = 0; mf < 4; ++mf)
#pragma unroll
                for (int nf = 0; nf < 4; ++nf) {
                    int cl = nf * 16 + lr;
                    int nl = wm * 64 + mf * 16 + g * 4;
                    *(f32x4*)&T[cl * TP + nl] = acc[mf][nf];
                }
        }
        __syncthreads();
#pragma unroll
        for (int pass = 0; pass < 8; ++pass) {
            int cl = pass * 8 + rq;
            int c = c0 + ch * 64 + cl;
            int n = n0 + lr5 * 4;
            f32x4 v = *(const f32x4*)&T[cl * TP + lr5 * 4];
            size_t base = ((size_t)b * CC + c) * CN + n;
            f32x4 q4 = *(const f32x4*)&query[base];
            f32x4 p4 = *(const f32x4*)&pe[(size_t)c * CN + n];
            float bias = bout[c];
#pragma unroll
            for (int j = 0; j < 4; ++j) v[j] = v[j] + bias + 2.0f * (q4[j] + p4[j]);
            *(f32x4*)&out[base] = v;
        }
        __syncthreads();
    }
}

extern "C" void kernel_launch(void* const* d_in, const int* in_sizes, int n_in,
                              void* d_out, int out_size, void* d_ws, size_t ws_size,
                              hipStream_t stream) {
    const float* query = (const float*)d_in[0];
    const float* value = (const float*)d_in[1];
    const float* W_off = (const float*)d_in[2];
    const float* b_off = (const float*)d_in[3];
    const float* W_attn = (const float*)d_in[4];
    const float* b_attn = (const float*)d_in[5];
    const float* W_val = (const float*)d_in[6];
    const float* b_val = (const float*)d_in[7];
    const float* W_out = (const float*)d_in[8];
    const float* b_out = (const float*)d_in[9];
    float* out = (float*)d_out;

    char* p = (char*)d_ws;
    float* pe = (float*)p;            p += (size_t)CC * CN * 4;
    bf16* Wv_bf = (bf16*)p;           p += (size_t)CC * CC * 2;
    bf16* Wout_bf = (bf16*)p;         p += (size_t)CC * CC * 2;
    bf16* W96_bf = (bf16*)p;          p += (size_t)96 * CC * 2 + 256;
    bf16* v_s = (bf16*)p;             p += (size_t)CB * NHEADS * CN * HDIM * 2;
    bf16* s_t = (bf16*)p;             p += (size_t)CB * CN * CC * 2;

    pe_pack<<<dim3((CC * CN + 255) / 256), dim3(256), 0, stream>>>(pe, W_val, W_off, W_attn,
                                                                   W_out, Wv_bf, W96_bf, Wout_bf);
    vproj_g<<<dim3(CN / 64, 2, CB), dim3(256), 0, stream>>>(value, Wv_bf, b_val, v_s);
    offattn_sample<<<dim3(1024), dim3(256), 0, stream>>>(query, pe, W96_bf,
                                                         b_off, b_attn, v_s, s_t);
    outproj_v7<<<dim3(1024), dim3(256), 0, stream>>>(s_t, Wout_bf, b_out, query, pe, out);
}